// Round 7
// baseline (5170.989 us; speedup 1.0000x reference)
//
#include <hip/hip_runtime.h>

typedef _Float16 half8 __attribute__((ext_vector_type(8)));
typedef float floatx4 __attribute__((ext_vector_type(4)));
typedef float floatx2 __attribute__((ext_vector_type(2)));

#define B_   8
#define N_   4096
#define S_   2048
#define K_   64
#define CIN  64
#define HID_ 128
#define Q_   (B_*S_)

// ---------------- ws layout (bytes), total ~2.26 MB ----------------
#define WS_STATS 0u          // 512 u64 (sum0,sq0,sum1,sq1) = 4096
#define WS_CNTT  4096u       // int, padded
#define WS_W0T   4224u       // 128*96 f16 = 24576
#define WS_W1T   28800u      // 128*128 f16 = 32768
#define WS_W2T   61568u      // 32768
#define WS_SC0   94336u      // 128 f32
#define WS_SH0   94848u
#define WS_SC1   95360u
#define WS_SH1   95872u
#define WS_CNT   96384u      // 16384 int = 65536
#define WS_NBR   161920u     // 16384*64 u16 = 2097152
// end ~2259072

// ---------------------------------------------------------------- prep
__global__ __launch_bounds__(256) void k_prep(const float* __restrict__ W0,
        const float* __restrict__ W1, const float* __restrict__ W2,
        _Float16* __restrict__ w0t, _Float16* __restrict__ w1t, _Float16* __restrict__ w2t,
        unsigned long long* __restrict__ stats, int* __restrict__ cntT) {
    int t = blockIdx.x * 256 + threadIdx.x;
    if (t < 128 * 96) {                       // W0T[c][k], k padded 67->96 with 0
        int c = t / 96, k = t - c * 96;
        w0t[t] = (k < 67) ? (_Float16)W0[k * 128 + c] : (_Float16)0.f;
    } else if (t < 128 * 96 + 16384) {        // W1T[c][k]
        int u = t - 128 * 96; int c = u >> 7, k = u & 127;
        w1t[u] = (_Float16)W1[k * 128 + c];
    } else if (t < 128 * 96 + 32768) {        // W2T[c][k]
        int u = t - 128 * 96 - 16384; int c = u >> 7, k = u & 127;
        w2t[u] = (_Float16)W2[k * 128 + c];
    }
    if (t < 512) stats[t] = 0ULL;
    if (t == 0) *cntT = 0;
}

// ---------------------------------------------------------------- FPS
// SINGLE WAVE per cloud + exact group pruning.
//  - 64 lanes x 64 pts in registers; no __syncthreads in the loop.
//  - one-time spatial counting sort -> 256 groups of 16 consecutive sorted
//    points; per-group bounding sphere (q, r) and running groupmax.
//  - skip group iff dist(c,q) >= r + sqrt(groupmax) + 1e-4: then every
//    point's new distance >= its md, so the min() update is a provable
//    no-op (margin >> f32 rounding). Non-skipped groups update with
//    byte-identical arithmetic (contract off, numpy order) -> md values
//    EXACTLY equal the full-update values at all times.
//  - argmax: wave DPP float-max of groupmaxes -> readlane -> equality
//    extract of (0xFFFF-origidx) among md==wmax -> wave DPP u32-max ->
//    smallest ORIGINAL index among global-max points == numpy argmax,
//    independent of the (nondeterministic) sort permutation.
template<int CTRL>
__device__ inline float dppmaxf(float v) {
    int iv = __builtin_bit_cast(int, v);
    int sh = __builtin_amdgcn_update_dpp(iv, iv, CTRL, 0xF, 0xF, false);
    return fmaxf(v, __builtin_bit_cast(float, sh));
}
template<int CTRL>
__device__ inline unsigned dppmaxu(unsigned v) {
    int iv = (int)v;
    int sh = __builtin_amdgcn_update_dpp(iv, iv, CTRL, 0xF, 0xF, false);
    unsigned s = (unsigned)sh;
    return v > s ? v : s;
}

__global__ __launch_bounds__(64, 1) void k_fps(const float* __restrict__ pos,
        float* __restrict__ outCtr, float* __restrict__ outBatch) {
    __shared__ __align__(16) float4 sP4[N_];      // by ORIGINAL index (64 KB)
    __shared__ __align__(16) float4 sSort[N_];    // sorted (x,y,z,idx-bits) (64 KB)
    __shared__ int hist[256];
    __shared__ unsigned short sSeq[S_];
    int b = blockIdx.x, lane = threadIdx.x;
    const float* P = pos + (size_t)b * N_ * 3;

    for (int c = lane; c < 256; c += 64) hist[c] = 0;
    __syncthreads();
    // ---- pass 1: load, write sP4[origidx], histogram cells
    #pragma unroll
    for (int ch = 0; ch < 4; ch++) {
        int p0 = lane * 64 + ch * 16;
        const float4* vp = (const float4*)(P + (size_t)p0 * 3);
        float a[48];
        #pragma unroll
        for (int v = 0; v < 12; v++) {
            float4 t4 = vp[v];
            a[v*4] = t4.x; a[v*4+1] = t4.y; a[v*4+2] = t4.z; a[v*4+3] = t4.w;
        }
        #pragma unroll
        for (int j = 0; j < 16; j++) {
            float x = a[3*j], y = a[3*j+1], z = a[3*j+2];
            sP4[p0 + j] = make_float4(x, y, z, 0.f);
            int cx = min(7, max(0, (int)(x * 8.f)));
            int cy = min(7, max(0, (int)(y * 8.f)));
            int cz = min(3, max(0, (int)(z * 4.f)));
            atomicAdd(&hist[(cz * 8 + cy) * 8 + cx], 1);
        }
    }
    __syncthreads();
    if (lane == 0) {       // serial exclusive prefix (once, ~5us)
        int acc = 0;
        for (int c = 0; c < 256; c++) { int t = hist[c]; hist[c] = acc; acc += t; }
    }
    __syncthreads();
    // ---- pass 2: scatter to sorted order (order within cell nondeterministic — safe)
    #pragma unroll
    for (int ch = 0; ch < 4; ch++) {
        int p0 = lane * 64 + ch * 16;
        #pragma unroll
        for (int j = 0; j < 16; j++) {
            float4 t4 = sP4[p0 + j];
            int cx = min(7, max(0, (int)(t4.x * 8.f)));
            int cy = min(7, max(0, (int)(t4.y * 8.f)));
            int cz = min(3, max(0, (int)(t4.z * 4.f)));
            int s = atomicAdd(&hist[(cz * 8 + cy) * 8 + cx], 1);
            sSort[s] = make_float4(t4.x, t4.y, t4.z, __uint_as_float((unsigned)(p0 + j)));
        }
    }
    __syncthreads();

    // ---- per-lane group state: 4 slots x 16 pts
    floatx2 PX[4][8], PY[4][8], PZ[4][8], MD[4][8];
    unsigned LO[4][8];                    // packed (0xFFFF-idx): [lo16 | hi16]
    float qx[4], qy[4], qz[4], rr[4], gmax[4];
    #pragma unroll
    for (int s = 0; s < 4; s++) {
        int base = (s * 64 + lane) * 16;
        float X[16], Y[16], Z[16]; unsigned ID[16];
        float sx = 0.f, sy = 0.f, sz = 0.f;
        #pragma unroll
        for (int j = 0; j < 16; j++) {
            float4 t4 = sSort[base + j];
            X[j] = t4.x; Y[j] = t4.y; Z[j] = t4.z; ID[j] = __float_as_uint(t4.w);
            sx += t4.x; sy += t4.y; sz += t4.z;
        }
        qx[s] = sx * 0.0625f; qy[s] = sy * 0.0625f; qz[s] = sz * 0.0625f;
        float mr2 = 0.f;
        #pragma unroll
        for (int j = 0; j < 16; j++) {
            float dx = X[j] - qx[s], dy = Y[j] - qy[s], dz = Z[j] - qz[s];
            mr2 = fmaxf(mr2, dx*dx + dy*dy + dz*dz);
        }
        rr[s] = sqrtf(mr2) * 1.0001f + 1e-6f;
        #pragma unroll
        for (int k = 0; k < 8; k++) {
            PX[s][k][0] = X[2*k]; PX[s][k][1] = X[2*k+1];
            PY[s][k][0] = Y[2*k]; PY[s][k][1] = Y[2*k+1];
            PZ[s][k][0] = Z[2*k]; PZ[s][k][1] = Z[2*k+1];
            MD[s][k][0] = __builtin_inff(); MD[s][k][1] = __builtin_inff();
            LO[s][k] = (0xFFFFu - ID[2*k]) | ((0xFFFFu - ID[2*k+1]) << 16);
        }
        gmax[s] = __builtin_inff();
    }

    // ---- main loop: no barriers, no global stores
    int last = 0;
    float4 cc = sP4[0];
    for (int i = 0; i < S_; i++) {
        if (lane == (i & 63)) sSeq[i] = (unsigned short)last;
        float ccx = cc.x, ccy = cc.y, ccz = cc.z;
        #pragma unroll
        for (int s = 0; s < 4; s++) {
            float ddx = ccx - qx[s], ddy = ccy - qy[s], ddz = ccz - qz[s];
            float D2 = ddx*ddx + ddy*ddy + ddz*ddz;
            if (sqrtf(D2) < rr[s] + sqrtf(gmax[s]) + 1e-4f) {   // else provable no-op
                #pragma clang fp contract(off)
                floatx2 cx2 = {ccx, ccx}, cy2 = {ccy, ccy}, cz2 = {ccz, ccz};
                floatx2 gm2 = {-1.f, -1.f};
                #pragma unroll
                for (int k = 0; k < 8; k++) {
                    floatx2 dx = PX[s][k] - cx2, dy = PY[s][k] - cy2, dz = PZ[s][k] - cz2;
                    floatx2 d = (dx * dx + dy * dy) + dz * dz;   // numpy order, no fma
                    floatx2 nm = __builtin_elementwise_min(MD[s][k], d);
                    MD[s][k] = nm;
                    gm2 = __builtin_elementwise_max(gm2, nm);
                }
                gmax[s] = fmaxf(gm2[0], gm2[1]);
            }
        }
        // wave float-max of groupmaxes
        float wm = fmaxf(fmaxf(gmax[0], gmax[1]), fmaxf(gmax[2], gmax[3]));
        wm = dppmaxf<0x111>(wm);
        wm = dppmaxf<0x112>(wm);
        wm = dppmaxf<0x114>(wm);
        wm = dppmaxf<0x118>(wm);
        wm = dppmaxf<0x142>(wm);
        wm = dppmaxf<0x143>(wm);
        float wmax = __builtin_bit_cast(float,
                __builtin_amdgcn_readlane(__builtin_bit_cast(int, wm), 63));
        // exact first-original-index extraction among md==wmax
        unsigned cand = 0;
        #pragma unroll
        for (int s = 0; s < 4; s++) {
            if (gmax[s] == wmax) {
                unsigned c2 = 0;
                #pragma unroll
                for (int k = 0; k < 8; k++) {
                    unsigned l0 = LO[s][k] & 0xFFFFu, l1 = LO[s][k] >> 16;
                    if (MD[s][k][0] == wmax && l0 > c2) c2 = l0;
                    if (MD[s][k][1] == wmax && l1 > c2) c2 = l1;
                }
                if (c2 > cand) cand = c2;
            }
        }
        cand = dppmaxu<0x111>(cand);
        cand = dppmaxu<0x112>(cand);
        cand = dppmaxu<0x114>(cand);
        cand = dppmaxu<0x118>(cand);
        cand = dppmaxu<0x142>(cand);
        cand = dppmaxu<0x143>(cand);
        unsigned glo = (unsigned)__builtin_amdgcn_readlane((int)cand, 63);
        last = (int)(0xFFFFu - glo);
        cc = sP4[last];                        // broadcast ds_read_b128
    }
    __syncthreads();
    for (int i = lane; i < S_; i += 64) {      // bulk write-out (once)
        int o = b * S_ + i;
        float4 c = sP4[sSeq[i]];
        outCtr[o*3] = c.x; outCtr[o*3+1] = c.y; outCtr[o*3+2] = c.z;
        outBatch[o] = (float)b;
    }
}

// ---------------------------------------------------------------- radius-KNN (exact rank select)
__global__ __launch_bounds__(256) void k_nbr(const float* __restrict__ pos,
        const float* __restrict__ ctr, unsigned short* __restrict__ nbr,
        int* __restrict__ cnt, int* __restrict__ cntT) {
    __shared__ float cD[1024];
    __shared__ unsigned short cI[1024];
    __shared__ int cN;
    int q = blockIdx.x, tid = threadIdx.x;
    int b = q >> 11;
    if (tid == 0) cN = 0;
    __syncthreads();
    float cx = ctr[q*3], cy = ctr[q*3+1], cz = ctr[q*3+2];
    const float* P = pos + (size_t)b * N_ * 3;
    float a[48];
    {
        const float4* vp = (const float4*)(P + (size_t)tid * 48);
        #pragma unroll
        for (int v = 0; v < 12; v++) {
            float4 t4 = vp[v];
            a[v*4] = t4.x; a[v*4+1] = t4.y; a[v*4+2] = t4.z; a[v*4+3] = t4.w;
        }
    }
    unsigned msk = 0;
    float d2a[16];
    {
        #pragma clang fp contract(off)
        #pragma unroll
        for (int j = 0; j < 16; j++) {
            float dx = cx - a[3*j], dy = cy - a[3*j+1], dz = cz - a[3*j+2];
            float d2 = (dx * dx + dy * dy) + dz * dz;
            d2a[j] = d2;
            if (d2 <= 0.04f) msk |= 1u << j;     // f32(0.2**2) boundary, exact
        }
    }
    int myc = __popc(msk);
    int base = 0;
    if (myc) base = atomicAdd(&cN, myc);         // one atomic per hitting thread
    unsigned mm = msk;
    while (mm) {
        int j = __builtin_ctz(mm); mm &= mm - 1;
        if (base < 1024) { cD[base] = d2a[j]; cI[base] = (unsigned short)(tid * 16 + j); }
        base++;
    }
    __syncthreads();
    int M = min(cN, 1024);
    int V = min(M, K_);
    for (int i = tid; i < M; i += 256) {
        float di = cD[i]; int ii = (int)cI[i]; int r = 0;
        for (int j = 0; j < M; j++) {
            float dj = cD[j];
            r += (dj < di) || (dj == di && (int)cI[j] < ii);   // stable top_k tie-break
        }
        if (r < K_) nbr[q * K_ + r] = (unsigned short)ii;      // rank IS the slot
    }
    if (tid == 0) { cnt[q] = V; atomicAdd(cntT, V); }
}

// ---------------------------------------------------------------- BN params
__global__ void k_bnparam(const unsigned long long* __restrict__ stats, const int* __restrict__ cntT,
        const float* __restrict__ g, const float* __restrict__ be,
        float* __restrict__ scale, float* __restrict__ shift) {
    int t = threadIdx.x;
    double c = (double)(*cntT);
    double mean = (double)(long long)stats[t] * (1.0 / 1048576.0) / c;
    double ex2  = (double)(long long)stats[128 + t] * (1.0 / 1048576.0) / c;
    double var = ex2 - mean * mean;
    if (var < 0.0) var = 0.0;
    double sc = (double)g[t] / sqrt(var + 1e-5);
    scale[t] = (float)sc;
    shift[t] = (float)((double)be[t] - mean * sc);
}

// ---------------------------------------------------------------- fused MLP pass (recompute pipeline)
template<int STAGE>
__global__ __launch_bounds__(256) void k_mlp(const float* __restrict__ x,
        const float* __restrict__ pos, const float* __restrict__ ctr,
        const unsigned short* __restrict__ nbr, const int* __restrict__ cnt,
        const _Float16* __restrict__ w0t, const _Float16* __restrict__ w1t,
        const _Float16* __restrict__ w2t,
        const float* __restrict__ b0, const float* __restrict__ b1,
        const float* __restrict__ b2,
        const float* __restrict__ sc0, const float* __restrict__ sh0,
        const float* __restrict__ sc1, const float* __restrict__ sh1,
        unsigned long long* __restrict__ statsOut, float* __restrict__ outF) {
    __shared__ __align__(16) _Float16 sW0[128 * 104];
    __shared__ __align__(16) _Float16 sW1[(STAGE >= 1) ? 128 * 136 : 8];
    __shared__ __align__(16) _Float16 sW2[(STAGE >= 2) ? 128 * 136 : 8];
    __shared__ __align__(16) _Float16 sBuf[64 * 136];   // feat(104) / h'(136) stage
    __shared__ float sSum[(STAGE <= 1) ? 512 : 4];
    __shared__ float sSq [(STAGE <= 1) ? 512 : 4];
    __shared__ float sMax[(STAGE == 2) ? 512 : 4];
    __shared__ unsigned short sNbr[64];
    __shared__ float sB0v[128];
    __shared__ float sB1v[(STAGE >= 1) ? 128 : 4];
    __shared__ float sSc0[(STAGE >= 1) ? 128 : 4];
    __shared__ float sSh0[(STAGE >= 1) ? 128 : 4];
    __shared__ float sB2v[(STAGE >= 2) ? 128 : 4];
    __shared__ float sSc1[(STAGE >= 2) ? 128 : 4];
    __shared__ float sSh1[(STAGE >= 2) ? 128 : 4];

    int tid = threadIdx.x, wid = tid >> 6, lane = tid & 63;
    int lr = lane & 15, lq = lane >> 4;

    {   // stage W0T (stride 104 f16 = 52 dwords: conflict-spread)
        const unsigned* src = (const unsigned*)w0t;
        unsigned* dst = (unsigned*)sW0;
        for (int i = tid; i < 6144; i += 256) { int r = i / 48, c = i - r * 48; dst[r*52 + c] = src[i]; }
    }
    if constexpr (STAGE >= 1) {
        const unsigned* src = (const unsigned*)w1t;
        unsigned* dst = (unsigned*)sW1;
        for (int i = tid; i < 8192; i += 256) { int r = i >> 6, c = i & 63; dst[r*68 + c] = src[i]; }
    }
    if constexpr (STAGE >= 2) {
        const unsigned* src = (const unsigned*)w2t;
        unsigned* dst = (unsigned*)sW2;
        for (int i = tid; i < 8192; i += 256) { int r = i >> 6, c = i & 63; dst[r*68 + c] = src[i]; }
    }
    if (tid < 128) {
        sB0v[tid] = b0[tid];
        if constexpr (STAGE >= 1) { sB1v[tid] = b1[tid]; sSc0[tid] = sc0[tid]; sSh0[tid] = sh0[tid]; }
        if constexpr (STAGE >= 2) { sB2v[tid] = b2[tid]; sSc1[tid] = sc1[tid]; sSh1[tid] = sh1[tid]; }
    }
    if constexpr (STAGE <= 1)
        for (int i = tid; i < 512; i += 256) { sSum[i] = 0.f; sSq[i] = 0.f; }

    for (int qq = 0; qq < 8; qq++) {
        int q = blockIdx.x * 8 + qq;
        int b = q >> 11;
        __syncthreads();                    // prior-iter sBuf readers done
        int n = cnt[q];
        if (tid < 64) sNbr[tid] = nbr[q * K_ + tid];
        __syncthreads();
        {   // gather x_j -> feat cols 0..63 (f16), zero rows >= n
            int row = tid >> 2, c4 = (tid & 3) * 16;
            half8 o0, o1;
            #pragma unroll
            for (int e = 0; e < 8; e++) { o0[e] = (_Float16)0.f; o1[e] = (_Float16)0.f; }
            if (row < n) {
                const float4* xr = (const float4*)(x + ((size_t)b * N_ + sNbr[row]) * CIN + c4);
                float4 v0 = xr[0], v1 = xr[1], v2 = xr[2], v3 = xr[3];
                o0[0]=(_Float16)v0.x; o0[1]=(_Float16)v0.y; o0[2]=(_Float16)v0.z; o0[3]=(_Float16)v0.w;
                o0[4]=(_Float16)v1.x; o0[5]=(_Float16)v1.y; o0[6]=(_Float16)v1.z; o0[7]=(_Float16)v1.w;
                o1[0]=(_Float16)v2.x; o1[1]=(_Float16)v2.y; o1[2]=(_Float16)v2.z; o1[3]=(_Float16)v2.w;
                o1[4]=(_Float16)v3.x; o1[5]=(_Float16)v3.y; o1[6]=(_Float16)v3.z; o1[7]=(_Float16)v3.w;
            }
            *(half8*)&sBuf[row * 104 + c4]     = o0;
            *(half8*)&sBuf[row * 104 + c4 + 8] = o1;
        }
        if (tid < 64) {   // cols 64..66 = pos_j - ctr, 67..95 = 0
            half8 z, o;
            #pragma unroll
            for (int e = 0; e < 8; e++) { z[e] = (_Float16)0.f; o[e] = (_Float16)0.f; }
            if (tid < n) {
                int j = sNbr[tid];
                float cx = ctr[q*3], cy = ctr[q*3+1], cz = ctr[q*3+2];
                const float* pj = pos + ((size_t)b * N_ + j) * 3;
                o[0] = (_Float16)(pj[0] - cx); o[1] = (_Float16)(pj[1] - cy); o[2] = (_Float16)(pj[2] - cz);
            }
            *(half8*)&sBuf[tid * 104 + 64] = o;
            *(half8*)&sBuf[tid * 104 + 72] = z;
            *(half8*)&sBuf[tid * 104 + 80] = z;
            *(half8*)&sBuf[tid * 104 + 88] = z;
        }
        __syncthreads();

        // ---- GEMM0: K=96
        floatx4 acc[8];
        #pragma unroll
        for (int nt = 0; nt < 8; nt++)
            #pragma unroll
            for (int r = 0; r < 4; r++) acc[nt][r] = 0.f;
        #pragma unroll
        for (int ks = 0; ks < 3; ks++) {
            half8 av = *(const half8*)&sBuf[(wid * 16 + lr) * 104 + ks * 32 + lq * 8];
            #pragma unroll
            for (int nt = 0; nt < 8; nt++) {
                half8 bv = *(const half8*)&sW0[(nt * 16 + lr) * 104 + ks * 32 + lq * 8];
                acc[nt] = __builtin_amdgcn_mfma_f32_16x16x32_f16(av, bv, acc[nt], 0, 0, 0);
            }
        }
        __syncthreads();                    // all waves done reading feat
        int r0 = wid * 16 + lq * 4;

        if constexpr (STAGE == 0) {
            #pragma unroll
            for (int nt = 0; nt < 8; nt++) {
                int col = nt * 16 + lr;
                float bias = sB0v[col];
                float s1 = 0.f, s2 = 0.f;
                #pragma unroll
                for (int r = 0; r < 4; r++) {
                    float v = acc[nt][r] + bias;
                    if (r0 + r < n) { s1 += v; s2 += v * v; }
                }
                s1 += __shfl_xor(s1, 16); s1 += __shfl_xor(s1, 32);
                s2 += __shfl_xor(s2, 16); s2 += __shfl_xor(s2, 32);
                if (lq == 0) { sSum[wid * 128 + col] += s1; sSq[wid * 128 + col] += s2; }
            }
        } else {
            // BN0 + ReLU -> f16 A-matrix for GEMM1
            #pragma unroll
            for (int nt = 0; nt < 8; nt++) {
                int col = nt * 16 + lr;
                float bias = sB0v[col], s = sSc0[col], t2 = sSh0[col];
                #pragma unroll
                for (int r = 0; r < 4; r++) {
                    float v = (acc[nt][r] + bias) * s + t2;
                    sBuf[(r0 + r) * 136 + col] = (_Float16)fmaxf(v, 0.f);
                }
            }
            __syncthreads();
            // ---- GEMM1: K=128
            #pragma unroll
            for (int nt = 0; nt < 8; nt++)
                #pragma unroll
                for (int r = 0; r < 4; r++) acc[nt][r] = 0.f;
            #pragma unroll
            for (int ks = 0; ks < 4; ks++) {
                half8 av = *(const half8*)&sBuf[(wid * 16 + lr) * 136 + ks * 32 + lq * 8];
                #pragma unroll
                for (int nt = 0; nt < 8; nt++) {
                    half8 bv = *(const half8*)&sW1[(nt * 16 + lr) * 136 + ks * 32 + lq * 8];
                    acc[nt] = __builtin_amdgcn_mfma_f32_16x16x32_f16(av, bv, acc[nt], 0, 0, 0);
                }
            }
            __syncthreads();

            if constexpr (STAGE == 1) {
                #pragma unroll
                for (int nt = 0; nt < 8; nt++) {
                    int col = nt * 16 + lr;
                    float bias = sB1v[col];
                    float s1 = 0.f, s2 = 0.f;
                    #pragma unroll
                    for (int r = 0; r < 4; r++) {
                        float v = acc[nt][r] + bias;
                        if (r0 + r < n) { s1 += v; s2 += v * v; }
                    }
                    s1 += __shfl_xor(s1, 16); s1 += __shfl_xor(s1, 32);
                    s2 += __shfl_xor(s2, 16); s2 += __shfl_xor(s2, 32);
                    if (lq == 0) { sSum[wid * 128 + col] += s1; sSq[wid * 128 + col] += s2; }
                }
            } else {
                // BN1 + ReLU -> f16 A-matrix for GEMM2
                #pragma unroll
                for (int nt = 0; nt < 8; nt++) {
                    int col = nt * 16 + lr;
                    float bias = sB1v[col], s = sSc1[col], t2 = sSh1[col];
                    #pragma unroll
                    for (int r = 0; r < 4; r++) {
                        float v = (acc[nt][r] + bias) * s + t2;
                        sBuf[(r0 + r) * 136 + col] = (_Float16)fmaxf(v, 0.f);
                    }
                }
                __syncthreads();
                // ---- GEMM2: K=128
                #pragma unroll
                for (int nt = 0; nt < 8; nt++)
                    #pragma unroll
                    for (int r = 0; r < 4; r++) acc[nt][r] = 0.f;
                #pragma unroll
                for (int ks = 0; ks < 4; ks++) {
                    half8 av = *(const half8*)&sBuf[(wid * 16 + lr) * 136 + ks * 32 + lq * 8];
                    #pragma unroll
                    for (int nt = 0; nt < 8; nt++) {
                        half8 bv = *(const half8*)&sW2[(nt * 16 + lr) * 136 + ks * 32 + lq * 8];
                        acc[nt] = __builtin_amdgcn_mfma_f32_16x16x32_f16(av, bv, acc[nt], 0, 0, 0);
                    }
                }
                // masked max -> out
                #pragma unroll
                for (int nt = 0; nt < 8; nt++) {
                    int col = nt * 16 + lr;
                    float bias = sB2v[col];
                    float m = -__builtin_inff();
                    #pragma unroll
                    for (int r = 0; r < 4; r++)
                        if (r0 + r < n) m = fmaxf(m, acc[nt][r] + bias);
                    m = fmaxf(m, __shfl_xor(m, 16));
                    m = fmaxf(m, __shfl_xor(m, 32));
                    if (lq == 0) sMax[wid * 128 + col] = m;
                }
                __syncthreads();
                if (tid < 128) {
                    float m = fmaxf(fmaxf(sMax[tid], sMax[128 + tid]),
                                    fmaxf(sMax[256 + tid], sMax[384 + tid]));
                    outF[(size_t)q * 128 + tid] = m;
                }
            }
        }
    }
    if constexpr (STAGE <= 1) {
        __syncthreads();
        if (tid < 128) {   // fixed-point (2^20) i64 atomics: fast + deterministic
            float t1 = sSum[tid] + sSum[128 + tid] + sSum[256 + tid] + sSum[384 + tid];
            float t2 = sSq[tid] + sSq[128 + tid] + sSq[256 + tid] + sSq[384 + tid];
            atomicAdd(&statsOut[tid],       (unsigned long long)(long long)llrintf(t1 * 1048576.f));
            atomicAdd(&statsOut[128 + tid], (unsigned long long)(long long)llrintf(t2 * 1048576.f));
        }
    }
}

// ---------------------------------------------------------------- launch
extern "C" void kernel_launch(void* const* d_in, const int* in_sizes, int n_in,
                              void* d_out, int out_size, void* d_ws, size_t ws_size,
                              hipStream_t stream) {
    const float* x   = (const float*)d_in[0];
    const float* pos = (const float*)d_in[1];
    const float* W0  = (const float*)d_in[3];
    const float* b0  = (const float*)d_in[4];
    const float* g0  = (const float*)d_in[5];
    const float* be0 = (const float*)d_in[6];
    const float* W1  = (const float*)d_in[7];
    const float* b1  = (const float*)d_in[8];
    const float* g1  = (const float*)d_in[9];
    const float* be1 = (const float*)d_in[10];
    const float* W2  = (const float*)d_in[11];
    const float* b2  = (const float*)d_in[12];

    char* ws = (char*)d_ws;
    unsigned long long* stats = (unsigned long long*)(ws + WS_STATS);
    int* cntT = (int*)(ws + WS_CNTT);
    _Float16* w0t = (_Float16*)(ws + WS_W0T);
    _Float16* w1t = (_Float16*)(ws + WS_W1T);
    _Float16* w2t = (_Float16*)(ws + WS_W2T);
    float* sc0 = (float*)(ws + WS_SC0);
    float* sh0 = (float*)(ws + WS_SH0);
    float* sc1 = (float*)(ws + WS_SC1);
    float* sh1 = (float*)(ws + WS_SH1);
    int* cnt = (int*)(ws + WS_CNT);
    unsigned short* nbr = (unsigned short*)(ws + WS_NBR);

    float* outF = (float*)d_out;                  // [16384,128]
    float* outCtr = (float*)d_out + 2097152;      // [16384,3]
    float* outBatch = (float*)d_out + 2146304;    // [16384]

    k_prep<<<176, 256, 0, stream>>>(W0, W1, W2, w0t, w1t, w2t, stats, cntT);
    k_fps<<<B_, 64, 0, stream>>>(pos, outCtr, outBatch);
    k_nbr<<<Q_, 256, 0, stream>>>(pos, outCtr, nbr, cnt, cntT);
    k_mlp<0><<<Q_/8, 256, 0, stream>>>(x, pos, outCtr, nbr, cnt, w0t, w1t, w2t,
            b0, b1, b2, sc0, sh0, sc1, sh1, stats, outF);
    k_bnparam<<<1, 128, 0, stream>>>(stats, cntT, g0, be0, sc0, sh0);
    k_mlp<1><<<Q_/8, 256, 0, stream>>>(x, pos, outCtr, nbr, cnt, w0t, w1t, w2t,
            b0, b1, b2, sc0, sh0, sc1, sh1, stats + 256, outF);
    k_bnparam<<<1, 128, 0, stream>>>(stats + 256, cntT, g1, be1, sc1, sh1);
    k_mlp<2><<<Q_/8, 256, 0, stream>>>(x, pos, outCtr, nbr, cnt, w0t, w1t, w2t,
            b0, b1, b2, sc0, sh0, sc1, sh1, stats, outF);
}

// Round 8
// 1955.955 us; speedup vs baseline: 2.6437x; 2.6437x over previous
//
#include <hip/hip_runtime.h>

typedef _Float16 half8 __attribute__((ext_vector_type(8)));
typedef float floatx4 __attribute__((ext_vector_type(4)));

#define B_   8
#define N_   4096
#define S_   2048
#define K_   64
#define CIN  64
#define HID_ 128
#define Q_   (B_*S_)

// ---------------- ws layout (bytes), total ~2.26 MB ----------------
#define WS_STATS 0u          // 512 u64 (sum0,sq0,sum1,sq1) = 4096
#define WS_CNTT  4096u       // int, padded
#define WS_W0T   4224u       // 128*96 f16 = 24576
#define WS_W1T   28800u      // 128*128 f16 = 32768
#define WS_W2T   61568u      // 32768
#define WS_SC0   94336u      // 128 f32
#define WS_SH0   94848u
#define WS_SC1   95360u
#define WS_SH1   95872u
#define WS_CNT   96384u      // 16384 int = 65536
#define WS_NBR   161920u     // 16384*64 u16 = 2097152
// end ~2259072

// ---------------------------------------------------------------- prep
__global__ __launch_bounds__(256) void k_prep(const float* __restrict__ W0,
        const float* __restrict__ W1, const float* __restrict__ W2,
        _Float16* __restrict__ w0t, _Float16* __restrict__ w1t, _Float16* __restrict__ w2t,
        unsigned long long* __restrict__ stats, int* __restrict__ cntT) {
    int t = blockIdx.x * 256 + threadIdx.x;
    if (t < 128 * 96) {                       // W0T[c][k], k padded 67->96 with 0
        int c = t / 96, k = t - c * 96;
        w0t[t] = (k < 67) ? (_Float16)W0[k * 128 + c] : (_Float16)0.f;
    } else if (t < 128 * 96 + 16384) {        // W1T[c][k]
        int u = t - 128 * 96; int c = u >> 7, k = u & 127;
        w1t[u] = (_Float16)W1[k * 128 + c];
    } else if (t < 128 * 96 + 32768) {        // W2T[c][k]
        int u = t - 128 * 96 - 16384; int c = u >> 7, k = u & 127;
        w2t[u] = (_Float16)W2[k * 128 + c];
    }
    if (t < 512) stats[t] = 0ULL;
    if (t == 0) *cntT = 0;
}

// ---------------------------------------------------------------- FPS
// r3-exact — best measured (1316us). DO NOT restructure: r4 packed (1394),
// r5 SALU-mix (1810), r7 single-wave+prune (4224) all regressed. 8 blocks x
// 256 threads, 16 pts/thread; u64 packed (distbits<<32 | ~idx) pure-VALU DPP
// max-reduce; no global stores in loop; ONE barrier/iter, double-buffered
// slots. Bit-exact vs numpy: contract OFF, numpy eval order, first-index
// argmax tie-break.
template<int CTRL>
__device__ inline unsigned long long dpp64(unsigned long long v) {
    int lo = (int)(unsigned)v, hi = (int)(unsigned)(v >> 32);
    int nlo = __builtin_amdgcn_update_dpp(lo, lo, CTRL, 0xF, 0xF, false);
    int nhi = __builtin_amdgcn_update_dpp(hi, hi, CTRL, 0xF, 0xF, false);
    return ((unsigned long long)(unsigned)nhi << 32) | (unsigned long long)(unsigned)nlo;
}
__device__ inline unsigned long long u64max(unsigned long long a, unsigned long long b) {
    return (b > a) ? b : a;
}

__global__ __launch_bounds__(256) void k_fps(const float* __restrict__ pos,
        float* __restrict__ outCtr, float* __restrict__ outBatch) {
    __shared__ __align__(16) float4 sP4[N_];                  // 64 KB
    __shared__ __align__(16) unsigned long long red[2][4];
    __shared__ unsigned short sSeq[S_];                       // 4 KB
    int b = blockIdx.x, tid = threadIdx.x;
    const float* P = pos + (size_t)b * N_ * 3;

    float px[16], py[16], pz[16], md[16];
    {
        const float4* vp = (const float4*)(P + tid * 48);
        float a[48];
        #pragma unroll
        for (int v = 0; v < 12; v++) {
            float4 t4 = vp[v];
            a[v*4] = t4.x; a[v*4+1] = t4.y; a[v*4+2] = t4.z; a[v*4+3] = t4.w;
        }
        #pragma unroll
        for (int j = 0; j < 16; j++) {
            px[j] = a[3*j]; py[j] = a[3*j+1]; pz[j] = a[3*j+2];
            md[j] = __builtin_inff();
            sP4[tid * 16 + j] = make_float4(px[j], py[j], pz[j], 0.f);
        }
    }
    __syncthreads();

    int last = 0;
    for (int i = 0; i < S_; i++) {
        float4 cc = sP4[last];                       // broadcast ds_read_b128
        if (tid == (i & 255)) sSeq[i] = (unsigned short)last;
        unsigned long long best;
        {
            #pragma clang fp contract(off)
            float bv = -1.f; unsigned bi = 0;
            #pragma unroll
            for (int j = 0; j < 16; j++) {
                float dx = px[j] - cc.x, dy = py[j] - cc.y, dz = pz[j] - cc.z;
                float d = (dx * dx + dy * dy) + dz * dz;   // numpy order, no fma
                float m = fminf(md[j], d); md[j] = m;
                if (m > bv) { bv = m; bi = (unsigned)j; } // strict > => first index
            }
            best = ((unsigned long long)__float_as_uint(bv) << 32)
                 | (unsigned long long)(0xFFFFu - (unsigned)(tid * 16) - bi);
        }
        best = u64max(best, dpp64<0x111>(best));   // row_shr:1
        best = u64max(best, dpp64<0x112>(best));   // row_shr:2
        best = u64max(best, dpp64<0x114>(best));   // row_shr:4
        best = u64max(best, dpp64<0x118>(best));   // row_shr:8
        best = u64max(best, dpp64<0x142>(best));   // row_bcast:15
        best = u64max(best, dpp64<0x143>(best));   // row_bcast:31 -> lane63 = wave max
        if ((tid & 63) == 63) red[i & 1][tid >> 6] = best;
        __syncthreads();   // double-buffered red: one barrier per iter is race-free
        ulonglong2 ra = *(const ulonglong2*)&red[i & 1][0];
        ulonglong2 rb = *(const ulonglong2*)&red[i & 1][2];
        unsigned long long g = u64max(u64max(ra.x, ra.y), u64max(rb.x, rb.y));
        last = (int)(0xFFFFu - (unsigned)(g & 0xFFFFu));
    }
    __syncthreads();
    for (int i = tid; i < S_; i += 256) {    // bulk write-out (once)
        int o = b * S_ + i;
        float4 c = sP4[sSeq[i]];
        outCtr[o*3] = c.x; outCtr[o*3+1] = c.y; outCtr[o*3+2] = c.z;
        outBatch[o] = (float)b;
    }
}

// ---------------------------------------------------------------- radius-KNN (exact rank select)
__global__ __launch_bounds__(256) void k_nbr(const float* __restrict__ pos,
        const float* __restrict__ ctr, unsigned short* __restrict__ nbr,
        int* __restrict__ cnt, int* __restrict__ cntT) {
    __shared__ float cD[1024];
    __shared__ unsigned short cI[1024];
    __shared__ int cN;
    int q = blockIdx.x, tid = threadIdx.x;
    int b = q >> 11;
    if (tid == 0) cN = 0;
    __syncthreads();
    float cx = ctr[q*3], cy = ctr[q*3+1], cz = ctr[q*3+2];
    const float* P = pos + (size_t)b * N_ * 3;
    float a[48];
    {
        const float4* vp = (const float4*)(P + (size_t)tid * 48);
        #pragma unroll
        for (int v = 0; v < 12; v++) {
            float4 t4 = vp[v];
            a[v*4] = t4.x; a[v*4+1] = t4.y; a[v*4+2] = t4.z; a[v*4+3] = t4.w;
        }
    }
    unsigned msk = 0;
    float d2a[16];
    {
        #pragma clang fp contract(off)
        #pragma unroll
        for (int j = 0; j < 16; j++) {
            float dx = cx - a[3*j], dy = cy - a[3*j+1], dz = cz - a[3*j+2];
            float d2 = (dx * dx + dy * dy) + dz * dz;
            d2a[j] = d2;
            if (d2 <= 0.04f) msk |= 1u << j;     // f32(0.2**2) boundary, exact
        }
    }
    int myc = __popc(msk);
    int base = 0;
    if (myc) base = atomicAdd(&cN, myc);         // one atomic per hitting thread
    unsigned mm = msk;
    while (mm) {
        int j = __builtin_ctz(mm); mm &= mm - 1;
        if (base < 1024) { cD[base] = d2a[j]; cI[base] = (unsigned short)(tid * 16 + j); }
        base++;
    }
    __syncthreads();
    int M = min(cN, 1024);
    int V = min(M, K_);
    for (int i = tid; i < M; i += 256) {
        float di = cD[i]; int ii = (int)cI[i]; int r = 0;
        for (int j = 0; j < M; j++) {
            float dj = cD[j];
            r += (dj < di) || (dj == di && (int)cI[j] < ii);   // stable top_k tie-break
        }
        if (r < K_) nbr[q * K_ + r] = (unsigned short)ii;      // rank IS the slot
    }
    if (tid == 0) { cnt[q] = V; atomicAdd(cntT, V); }
}

// ---------------------------------------------------------------- BN params
__global__ void k_bnparam(const unsigned long long* __restrict__ stats, const int* __restrict__ cntT,
        const float* __restrict__ g, const float* __restrict__ be,
        float* __restrict__ scale, float* __restrict__ shift) {
    int t = threadIdx.x;
    double c = (double)(*cntT);
    double mean = (double)(long long)stats[t] * (1.0 / 1048576.0) / c;
    double ex2  = (double)(long long)stats[128 + t] * (1.0 / 1048576.0) / c;
    double var = ex2 - mean * mean;
    if (var < 0.0) var = 0.0;
    double sc = (double)g[t] / sqrt(var + 1e-5);
    scale[t] = (float)sc;
    shift[t] = (float)((double)be[t] - mean * sc);
}

// ---------------------------------------------------------------- fused MLP pass (recompute, col-sliced)
// r8 restructure: weights live in REGISTERS (query-invariant B-fragments),
// each wave owns a 32-col slice x all 64 rows (acc[rt 0..3][nt 0..1]).
// LDS ~20KB (was 85-118KB) -> 2 blocks/CU; stats/max epilogues are
// register-accumulated (waves own disjoint cols — no cross-wave LDS stage).
// Per-element MFMA K-order unchanged -> outputs bit-identical to r6.
template<int STAGE>
__global__ __launch_bounds__(256, 2) void k_mlp(const float* __restrict__ x,
        const float* __restrict__ pos, const float* __restrict__ ctr,
        const unsigned short* __restrict__ nbr, const int* __restrict__ cnt,
        const _Float16* __restrict__ w0t, const _Float16* __restrict__ w1t,
        const _Float16* __restrict__ w2t,
        const float* __restrict__ b0, const float* __restrict__ b1,
        const float* __restrict__ b2,
        const float* __restrict__ sc0, const float* __restrict__ sh0,
        const float* __restrict__ sc1, const float* __restrict__ sh1,
        unsigned long long* __restrict__ statsOut, float* __restrict__ outF) {
    __shared__ __align__(16) _Float16 sBuf[64 * 136];   // feat(104) / h'(136)
    __shared__ unsigned short sNbr[64];
    __shared__ float sB0v[128];
    __shared__ float sB1v[(STAGE >= 1) ? 128 : 4];
    __shared__ float sSc0[(STAGE >= 1) ? 128 : 4];
    __shared__ float sSh0[(STAGE >= 1) ? 128 : 4];
    __shared__ float sB2v[(STAGE >= 2) ? 128 : 4];
    __shared__ float sSc1[(STAGE >= 2) ? 128 : 4];
    __shared__ float sSh1[(STAGE >= 2) ? 128 : 4];

    int tid = threadIdx.x, wid = tid >> 6, lane = tid & 63;
    int lr = lane & 15, lq = lane >> 4;
    int colbase = 32 * wid + lr;              // + 16*nt

    // ---- query-invariant B-fragments -> registers (L2-hot, once per wave)
    half8 w0f[3][2];
    #pragma unroll
    for (int ks = 0; ks < 3; ks++)
        #pragma unroll
        for (int nt = 0; nt < 2; nt++)
            w0f[ks][nt] = *(const half8*)(w0t + (colbase + 16*nt) * 96 + ks * 32 + lq * 8);
    half8 w1f[(STAGE >= 1) ? 4 : 1][2];
    if constexpr (STAGE >= 1)
        #pragma unroll
        for (int ks = 0; ks < 4; ks++)
            #pragma unroll
            for (int nt = 0; nt < 2; nt++)
                w1f[ks][nt] = *(const half8*)(w1t + (colbase + 16*nt) * 128 + ks * 32 + lq * 8);
    half8 w2f[(STAGE >= 2) ? 4 : 1][2];
    if constexpr (STAGE >= 2)
        #pragma unroll
        for (int ks = 0; ks < 4; ks++)
            #pragma unroll
            for (int nt = 0; nt < 2; nt++)
                w2f[ks][nt] = *(const half8*)(w2t + (colbase + 16*nt) * 128 + ks * 32 + lq * 8);

    if (tid < 128) {
        sB0v[tid] = b0[tid];
        if constexpr (STAGE >= 1) { sB1v[tid] = b1[tid]; sSc0[tid] = sc0[tid]; sSh0[tid] = sh0[tid]; }
        if constexpr (STAGE >= 2) { sB2v[tid] = b2[tid]; sSc1[tid] = sc1[tid]; sSh1[tid] = sh1[tid]; }
    }
    float runS1[2] = {0.f, 0.f}, runS2[2] = {0.f, 0.f};   // STAGE<=1 col stats

    for (int qq = 0; qq < 8; qq++) {
        int q = blockIdx.x * 8 + qq;
        int b = q >> 11;
        __syncthreads();                    // prior-iter sBuf readers done
        int n = cnt[q];
        if (tid < 64) sNbr[tid] = nbr[q * K_ + tid];
        __syncthreads();
        {   // gather x_j -> feat cols 0..63 (f16), zero rows >= n
            int row = tid >> 2, c4 = (tid & 3) * 16;
            half8 o0, o1;
            #pragma unroll
            for (int e = 0; e < 8; e++) { o0[e] = (_Float16)0.f; o1[e] = (_Float16)0.f; }
            if (row < n) {
                const float4* xr = (const float4*)(x + ((size_t)b * N_ + sNbr[row]) * CIN + c4);
                float4 v0 = xr[0], v1 = xr[1], v2 = xr[2], v3 = xr[3];
                o0[0]=(_Float16)v0.x; o0[1]=(_Float16)v0.y; o0[2]=(_Float16)v0.z; o0[3]=(_Float16)v0.w;
                o0[4]=(_Float16)v1.x; o0[5]=(_Float16)v1.y; o0[6]=(_Float16)v1.z; o0[7]=(_Float16)v1.w;
                o1[0]=(_Float16)v2.x; o1[1]=(_Float16)v2.y; o1[2]=(_Float16)v2.z; o1[3]=(_Float16)v2.w;
                o1[4]=(_Float16)v3.x; o1[5]=(_Float16)v3.y; o1[6]=(_Float16)v3.z; o1[7]=(_Float16)v3.w;
            }
            *(half8*)&sBuf[row * 104 + c4]     = o0;
            *(half8*)&sBuf[row * 104 + c4 + 8] = o1;
        }
        if (tid < 64) {   // cols 64..66 = pos_j - ctr, 67..95 = 0
            half8 z, o;
            #pragma unroll
            for (int e = 0; e < 8; e++) { z[e] = (_Float16)0.f; o[e] = (_Float16)0.f; }
            if (tid < n) {
                int j = sNbr[tid];
                float cx = ctr[q*3], cy = ctr[q*3+1], cz = ctr[q*3+2];
                const float* pj = pos + ((size_t)b * N_ + j) * 3;
                o[0] = (_Float16)(pj[0] - cx); o[1] = (_Float16)(pj[1] - cy); o[2] = (_Float16)(pj[2] - cz);
            }
            *(half8*)&sBuf[tid * 104 + 64] = o;
            *(half8*)&sBuf[tid * 104 + 72] = z;
            *(half8*)&sBuf[tid * 104 + 80] = z;
            *(half8*)&sBuf[tid * 104 + 88] = z;
        }
        __syncthreads();

        // ---- GEMM0: K=96, rows via rt, cols via (wid,nt)
        floatx4 acc[4][2];
        #pragma unroll
        for (int rt = 0; rt < 4; rt++)
            #pragma unroll
            for (int nt = 0; nt < 2; nt++)
                #pragma unroll
                for (int r = 0; r < 4; r++) acc[rt][nt][r] = 0.f;
        #pragma unroll
        for (int ks = 0; ks < 3; ks++) {
            half8 av[4];
            #pragma unroll
            for (int rt = 0; rt < 4; rt++)
                av[rt] = *(const half8*)&sBuf[(rt * 16 + lr) * 104 + ks * 32 + lq * 8];
            #pragma unroll
            for (int rt = 0; rt < 4; rt++)
                #pragma unroll
                for (int nt = 0; nt < 2; nt++)
                    acc[rt][nt] = __builtin_amdgcn_mfma_f32_16x16x32_f16(av[rt], w0f[ks][nt], acc[rt][nt], 0, 0, 0);
        }
        __syncthreads();                    // all waves done reading feat

        if constexpr (STAGE == 0) {
            #pragma unroll
            for (int nt = 0; nt < 2; nt++) {
                int col = colbase + 16 * nt;
                float bias = sB0v[col];
                #pragma unroll
                for (int rt = 0; rt < 4; rt++) {
                    int r0 = rt * 16 + lq * 4;
                    #pragma unroll
                    for (int r = 0; r < 4; r++) {
                        float v = acc[rt][nt][r] + bias;
                        if (r0 + r < n) { runS1[nt] += v; runS2[nt] += v * v; }
                    }
                }
            }
        } else {
            // BN0 + ReLU -> f16 A-matrix for GEMM1
            #pragma unroll
            for (int nt = 0; nt < 2; nt++) {
                int col = colbase + 16 * nt;
                float bias = sB0v[col], s = sSc0[col], t2 = sSh0[col];
                #pragma unroll
                for (int rt = 0; rt < 4; rt++) {
                    int r0 = rt * 16 + lq * 4;
                    #pragma unroll
                    for (int r = 0; r < 4; r++) {
                        float v = (acc[rt][nt][r] + bias) * s + t2;
                        sBuf[(r0 + r) * 136 + col] = (_Float16)fmaxf(v, 0.f);
                    }
                }
            }
            __syncthreads();
            // ---- GEMM1: K=128
            #pragma unroll
            for (int rt = 0; rt < 4; rt++)
                #pragma unroll
                for (int nt = 0; nt < 2; nt++)
                    #pragma unroll
                    for (int r = 0; r < 4; r++) acc[rt][nt][r] = 0.f;
            #pragma unroll
            for (int ks = 0; ks < 4; ks++) {
                half8 av[4];
                #pragma unroll
                for (int rt = 0; rt < 4; rt++)
                    av[rt] = *(const half8*)&sBuf[(rt * 16 + lr) * 136 + ks * 32 + lq * 8];
                #pragma unroll
                for (int rt = 0; rt < 4; rt++)
                    #pragma unroll
                    for (int nt = 0; nt < 2; nt++)
                        acc[rt][nt] = __builtin_amdgcn_mfma_f32_16x16x32_f16(av[rt], w1f[ks][nt], acc[rt][nt], 0, 0, 0);
            }

            if constexpr (STAGE == 1) {
                #pragma unroll
                for (int nt = 0; nt < 2; nt++) {
                    int col = colbase + 16 * nt;
                    float bias = sB1v[col];
                    #pragma unroll
                    for (int rt = 0; rt < 4; rt++) {
                        int r0 = rt * 16 + lq * 4;
                        #pragma unroll
                        for (int r = 0; r < 4; r++) {
                            float v = acc[rt][nt][r] + bias;
                            if (r0 + r < n) { runS1[nt] += v; runS2[nt] += v * v; }
                        }
                    }
                }
            } else {
                __syncthreads();            // GEMM1 A-reads done before sBuf overwrite
                // BN1 + ReLU -> f16 A-matrix for GEMM2
                #pragma unroll
                for (int nt = 0; nt < 2; nt++) {
                    int col = colbase + 16 * nt;
                    float bias = sB1v[col], s = sSc1[col], t2 = sSh1[col];
                    #pragma unroll
                    for (int rt = 0; rt < 4; rt++) {
                        int r0 = rt * 16 + lq * 4;
                        #pragma unroll
                        for (int r = 0; r < 4; r++) {
                            float v = (acc[rt][nt][r] + bias) * s + t2;
                            sBuf[(r0 + r) * 136 + col] = (_Float16)fmaxf(v, 0.f);
                        }
                    }
                }
                __syncthreads();
                // ---- GEMM2: K=128
                #pragma unroll
                for (int rt = 0; rt < 4; rt++)
                    #pragma unroll
                    for (int nt = 0; nt < 2; nt++)
                        #pragma unroll
                        for (int r = 0; r < 4; r++) acc[rt][nt][r] = 0.f;
                #pragma unroll
                for (int ks = 0; ks < 4; ks++) {
                    half8 av[4];
                    #pragma unroll
                    for (int rt = 0; rt < 4; rt++)
                        av[rt] = *(const half8*)&sBuf[(rt * 16 + lr) * 136 + ks * 32 + lq * 8];
                    #pragma unroll
                    for (int rt = 0; rt < 4; rt++)
                        #pragma unroll
                        for (int nt = 0; nt < 2; nt++)
                            acc[rt][nt] = __builtin_amdgcn_mfma_f32_16x16x32_f16(av[rt], w2f[ks][nt], acc[rt][nt], 0, 0, 0);
                }
                // masked max over ALL rows (wave owns its cols) -> direct store
                #pragma unroll
                for (int nt = 0; nt < 2; nt++) {
                    int col = colbase + 16 * nt;
                    float bias = sB2v[col];
                    float m = -__builtin_inff();
                    #pragma unroll
                    for (int rt = 0; rt < 4; rt++) {
                        int r0 = rt * 16 + lq * 4;
                        #pragma unroll
                        for (int r = 0; r < 4; r++)
                            if (r0 + r < n) m = fmaxf(m, acc[rt][nt][r] + bias);
                    }
                    m = fmaxf(m, __shfl_xor(m, 16));
                    m = fmaxf(m, __shfl_xor(m, 32));
                    if (lq == 0) outF[(size_t)q * 128 + col] = m;
                }
            }
        }
    }
    if constexpr (STAGE <= 1) {
        #pragma unroll
        for (int nt = 0; nt < 2; nt++) {
            float s1 = runS1[nt], s2 = runS2[nt];
            s1 += __shfl_xor(s1, 16); s1 += __shfl_xor(s1, 32);
            s2 += __shfl_xor(s2, 16); s2 += __shfl_xor(s2, 32);
            if (lq == 0) {   // fixed-point (2^20) i64 atomics: fast + deterministic
                int col = colbase + 16 * nt;
                atomicAdd(&statsOut[col],       (unsigned long long)(long long)llrintf(s1 * 1048576.f));
                atomicAdd(&statsOut[128 + col], (unsigned long long)(long long)llrintf(s2 * 1048576.f));
            }
        }
    }
}

// ---------------------------------------------------------------- launch
extern "C" void kernel_launch(void* const* d_in, const int* in_sizes, int n_in,
                              void* d_out, int out_size, void* d_ws, size_t ws_size,
                              hipStream_t stream) {
    const float* x   = (const float*)d_in[0];
    const float* pos = (const float*)d_in[1];
    const float* W0  = (const float*)d_in[3];
    const float* b0  = (const float*)d_in[4];
    const float* g0  = (const float*)d_in[5];
    const float* be0 = (const float*)d_in[6];
    const float* W1  = (const float*)d_in[7];
    const float* b1  = (const float*)d_in[8];
    const float* g1  = (const float*)d_in[9];
    const float* be1 = (const float*)d_in[10];
    const float* W2  = (const float*)d_in[11];
    const float* b2  = (const float*)d_in[12];

    char* ws = (char*)d_ws;
    unsigned long long* stats = (unsigned long long*)(ws + WS_STATS);
    int* cntT = (int*)(ws + WS_CNTT);
    _Float16* w0t = (_Float16*)(ws + WS_W0T);
    _Float16* w1t = (_Float16*)(ws + WS_W1T);
    _Float16* w2t = (_Float16*)(ws + WS_W2T);
    float* sc0 = (float*)(ws + WS_SC0);
    float* sh0 = (float*)(ws + WS_SH0);
    float* sc1 = (float*)(ws + WS_SC1);
    float* sh1 = (float*)(ws + WS_SH1);
    int* cnt = (int*)(ws + WS_CNT);
    unsigned short* nbr = (unsigned short*)(ws + WS_NBR);

    float* outF = (float*)d_out;                  // [16384,128]
    float* outCtr = (float*)d_out + 2097152;      // [16384,3]
    float* outBatch = (float*)d_out + 2146304;    // [16384]

    k_prep<<<176, 256, 0, stream>>>(W0, W1, W2, w0t, w1t, w2t, stats, cntT);
    k_fps<<<B_, 256, 0, stream>>>(pos, outCtr, outBatch);
    k_nbr<<<Q_, 256, 0, stream>>>(pos, outCtr, nbr, cnt, cntT);
    k_mlp<0><<<Q_/8, 256, 0, stream>>>(x, pos, outCtr, nbr, cnt, w0t, w1t, w2t,
            b0, b1, b2, sc0, sh0, sc1, sh1, stats, outF);
    k_bnparam<<<1, 128, 0, stream>>>(stats, cntT, g0, be0, sc0, sh0);
    k_mlp<1><<<Q_/8, 256, 0, stream>>>(x, pos, outCtr, nbr, cnt, w0t, w1t, w2t,
            b0, b1, b2, sc0, sh0, sc1, sh1, stats + 256, outF);
    k_bnparam<<<1, 128, 0, stream>>>(stats + 256, cntT, g1, be1, sc1, sh1);
    k_mlp<2><<<Q_/8, 256, 0, stream>>>(x, pos, outCtr, nbr, cnt, w0t, w1t, w2t,
            b0, b1, b2, sc0, sh0, sc1, sh1, stats, outF);
}

// Round 9
// 1742.656 us; speedup vs baseline: 2.9673x; 1.1224x over previous
//
#include <hip/hip_runtime.h>

typedef _Float16 half8 __attribute__((ext_vector_type(8)));
typedef float floatx4 __attribute__((ext_vector_type(4)));

#define B_   8
#define N_   4096
#define S_   2048
#define K_   64
#define CIN  64
#define HID_ 128
#define Q_   (B_*S_)
#define NCONS 248            // consumer blocks in k_front (blocks 8..255)

// ---------------- ws layout (bytes) ----------------
#define WS_STATS 0u          // 512 u64 (sum0,sq0,sum1,sq1) = 4096
#define WS_CNTT  4096u       // int, padded
#define WS_W0T   4224u       // 128*96 f16 = 24576
#define WS_W1T   28800u      // 128*128 f16 = 32768
#define WS_W2T   61568u      // 32768
#define WS_SC0   94336u      // 128 f32
#define WS_SH0   94848u
#define WS_SC1   95360u
#define WS_SH1   95872u
#define WS_CNT   96384u      // 16384 int = 65536
#define WS_NBR   161920u     // 16384*64 u16 = 2097152
#define WS_PROG  2259072u    // 8 int flags
// end ~2259136

// ---------------------------------------------------------------- prep
__global__ __launch_bounds__(256) void k_prep(const float* __restrict__ W0,
        const float* __restrict__ W1, const float* __restrict__ W2,
        _Float16* __restrict__ w0t, _Float16* __restrict__ w1t, _Float16* __restrict__ w2t,
        unsigned long long* __restrict__ stats, int* __restrict__ cntT, int* __restrict__ prog) {
    int t = blockIdx.x * 256 + threadIdx.x;
    if (t < 128 * 96) {                       // W0T[c][k], k padded 67->96 with 0
        int c = t / 96, k = t - c * 96;
        w0t[t] = (k < 67) ? (_Float16)W0[k * 128 + c] : (_Float16)0.f;
    } else if (t < 128 * 96 + 16384) {        // W1T[c][k]
        int u = t - 128 * 96; int c = u >> 7, k = u & 127;
        w1t[u] = (_Float16)W1[k * 128 + c];
    } else if (t < 128 * 96 + 32768) {        // W2T[c][k]
        int u = t - 128 * 96 - 16384; int c = u >> 7, k = u & 127;
        w2t[u] = (_Float16)W2[k * 128 + c];
    }
    if (t < 512) stats[t] = 0ULL;
    if (t < 8) prog[t] = 0;
    if (t == 0) *cntT = 0;
}

// ---------------------------------------------------------------- front: FPS producers + nbr/mlp0 consumers
// Blocks 0..7: r3-exact FPS (best measured 1316us; r4/r5/r7 all regressed —
// loop untouched) + batched flush every 64 iters: agent-scope centroid
// stores -> barrier (drains vmcnt: stores at coherence point) -> release
// flag prog[b]=i+1. Blocks 8..255: per-query consumers, i-major order
// (k=i*8+b, stride 248 -> readiness-monotone); tid0 spins with s_sleep on
// agent-acquire prog[b], reads centroid coherently, then nbr (exact rank
// select) + gather+GEMM0+stats0 (r8 col-sliced, weights in registers).
// All math byte-identical to r8 -> outputs bit-identical; stats are
// order-independent fixed-point i64 atomics. LDS is a 70KB role-union ->
// 2 blocks/CU capacity for the 256-block grid (co-residency has 2x slack).
template<int CTRL>
__device__ inline unsigned long long dpp64(unsigned long long v) {
    int lo = (int)(unsigned)v, hi = (int)(unsigned)(v >> 32);
    int nlo = __builtin_amdgcn_update_dpp(lo, lo, CTRL, 0xF, 0xF, false);
    int nhi = __builtin_amdgcn_update_dpp(hi, hi, CTRL, 0xF, 0xF, false);
    return ((unsigned long long)(unsigned)nhi << 32) | (unsigned long long)(unsigned)nlo;
}
__device__ inline unsigned long long u64max(unsigned long long a, unsigned long long b) {
    return (b > a) ? b : a;
}

__global__ __launch_bounds__(256) void k_front(const float* __restrict__ pos,
        const float* __restrict__ x, const _Float16* __restrict__ w0t,
        const float* __restrict__ b0, float* outCtr, float* __restrict__ outBatch,
        unsigned short* __restrict__ nbrG, int* __restrict__ cnt, int* __restrict__ cntT,
        unsigned long long* __restrict__ statsOut, int* prog) {
    __shared__ __align__(16) char uLDS[69760];   // role union -> 2 blocks/CU
    int tid = threadIdx.x;

    if (blockIdx.x < 8) {
        // ================= PRODUCER (r3 FPS + batched flush) =================
        float4* sP4 = (float4*)uLDS;                               // 64 KB
        unsigned long long* red = (unsigned long long*)(uLDS + 65536);
        unsigned short* sSeq = (unsigned short*)(uLDS + 65600);    // 4 KB
        int b = blockIdx.x;
        const float* P = pos + (size_t)b * N_ * 3;

        float px[16], py[16], pz[16], md[16];
        {
            const float4* vp = (const float4*)(P + tid * 48);
            float a[48];
            #pragma unroll
            for (int v = 0; v < 12; v++) {
                float4 t4 = vp[v];
                a[v*4] = t4.x; a[v*4+1] = t4.y; a[v*4+2] = t4.z; a[v*4+3] = t4.w;
            }
            #pragma unroll
            for (int j = 0; j < 16; j++) {
                px[j] = a[3*j]; py[j] = a[3*j+1]; pz[j] = a[3*j+2];
                md[j] = __builtin_inff();
                sP4[tid * 16 + j] = make_float4(px[j], py[j], pz[j], 0.f);
            }
        }
        __syncthreads();

        int last = 0;
        for (int i = 0; i < S_; i++) {
            float4 cc = sP4[last];                       // broadcast ds_read_b128
            if (tid == (i & 255)) sSeq[i] = (unsigned short)last;
            unsigned long long best;
            {
                #pragma clang fp contract(off)
                float bv = -1.f; unsigned bi = 0;
                #pragma unroll
                for (int j = 0; j < 16; j++) {
                    float dx = px[j] - cc.x, dy = py[j] - cc.y, dz = pz[j] - cc.z;
                    float d = (dx * dx + dy * dy) + dz * dz;   // numpy order, no fma
                    float m = fminf(md[j], d); md[j] = m;
                    if (m > bv) { bv = m; bi = (unsigned)j; } // strict > => first index
                }
                best = ((unsigned long long)__float_as_uint(bv) << 32)
                     | (unsigned long long)(0xFFFFu - (unsigned)(tid * 16) - bi);
            }
            best = u64max(best, dpp64<0x111>(best));   // row_shr:1
            best = u64max(best, dpp64<0x112>(best));   // row_shr:2
            best = u64max(best, dpp64<0x114>(best));   // row_shr:4
            best = u64max(best, dpp64<0x118>(best));   // row_shr:8
            best = u64max(best, dpp64<0x142>(best));   // row_bcast:15
            best = u64max(best, dpp64<0x143>(best));   // row_bcast:31 -> lane63 = wave max
            if ((tid & 63) == 63) red[(i & 1) * 4 + (tid >> 6)] = best;
            __syncthreads();   // double-buffered red: one barrier/iter race-free
            ulonglong2 ra = *(const ulonglong2*)&red[(i & 1) * 4];
            ulonglong2 rb = *(const ulonglong2*)&red[(i & 1) * 4 + 2];
            unsigned long long g = u64max(u64max(ra.x, ra.y), u64max(rb.x, rb.y));
            last = (int)(0xFFFFu - (unsigned)(g & 0xFFFFu));
            if ((i & 63) == 63) {   // flush 64 centroids (off the per-iter path)
                if (tid < 64) {
                    int ii = i - 63 + tid;
                    float4 c = sP4[sSeq[ii]];
                    size_t o = (size_t)b * S_ + ii;
                    __hip_atomic_store(&outCtr[o*3],   c.x, __ATOMIC_RELAXED, __HIP_MEMORY_SCOPE_AGENT);
                    __hip_atomic_store(&outCtr[o*3+1], c.y, __ATOMIC_RELAXED, __HIP_MEMORY_SCOPE_AGENT);
                    __hip_atomic_store(&outCtr[o*3+2], c.z, __ATOMIC_RELAXED, __HIP_MEMORY_SCOPE_AGENT);
                    outBatch[o] = (float)b;
                }
                __syncthreads();   // implicit vmcnt(0): stores at coherence point
                if (tid == 0)
                    __hip_atomic_store(&prog[b], i + 1, __ATOMIC_RELEASE, __HIP_MEMORY_SCOPE_AGENT);
            }
        }
    } else {
        // ================= CONSUMER (nbr + mlp stage0 per query) =================
        float* cD = (float*)uLDS;                          // 4 KB
        unsigned short* cI = (unsigned short*)(uLDS + 4096);
        unsigned short* sNbr = (unsigned short*)(uLDS + 6144);
        float* sB0v = (float*)(uLDS + 6272);
        float* sCtr = (float*)(uLDS + 6784);
        int* cN = (int*)(uLDS + 6800);
        _Float16* sBuf = (_Float16*)(uLDS + 6912);         // 64*104 f16

        int wid = tid >> 6, lane = tid & 63;
        int lr = lane & 15, lq = lane >> 4;
        int colbase = 32 * wid + lr;
        half8 w0f[3][2];
        #pragma unroll
        for (int ks = 0; ks < 3; ks++)
            #pragma unroll
            for (int nt = 0; nt < 2; nt++)
                w0f[ks][nt] = *(const half8*)(w0t + (colbase + 16*nt) * 96 + ks * 32 + lq * 8);
        if (tid < 128) sB0v[tid] = b0[tid];
        float runS1[2] = {0.f, 0.f}, runS2[2] = {0.f, 0.f};

        for (int k = (int)blockIdx.x - 8; k < Q_; k += NCONS) {
            int i = k >> 3, b = k & 7;
            int q = (b << 11) + i;
            if (tid == 0) {
                while (__hip_atomic_load(&prog[b], __ATOMIC_ACQUIRE, __HIP_MEMORY_SCOPE_AGENT) <= i)
                    __builtin_amdgcn_s_sleep(32);
                sCtr[0] = __hip_atomic_load(&outCtr[(size_t)q*3],   __ATOMIC_RELAXED, __HIP_MEMORY_SCOPE_AGENT);
                sCtr[1] = __hip_atomic_load(&outCtr[(size_t)q*3+1], __ATOMIC_RELAXED, __HIP_MEMORY_SCOPE_AGENT);
                sCtr[2] = __hip_atomic_load(&outCtr[(size_t)q*3+2], __ATOMIC_RELAXED, __HIP_MEMORY_SCOPE_AGENT);
                *cN = 0;
            }
            __syncthreads();   // B1
            float cx = sCtr[0], cy = sCtr[1], cz = sCtr[2];
            const float* P = pos + (size_t)b * N_ * 3;
            float a[48];
            {
                const float4* vp = (const float4*)(P + (size_t)tid * 48);
                #pragma unroll
                for (int v = 0; v < 12; v++) {
                    float4 t4 = vp[v];
                    a[v*4] = t4.x; a[v*4+1] = t4.y; a[v*4+2] = t4.z; a[v*4+3] = t4.w;
                }
            }
            unsigned msk = 0;
            float d2a[16];
            {
                #pragma clang fp contract(off)
                #pragma unroll
                for (int j = 0; j < 16; j++) {
                    float dx = cx - a[3*j], dy = cy - a[3*j+1], dz = cz - a[3*j+2];
                    float d2 = (dx * dx + dy * dy) + dz * dz;
                    d2a[j] = d2;
                    if (d2 <= 0.04f) msk |= 1u << j;     // f32(0.2**2) boundary, exact
                }
            }
            int myc = __popc(msk);
            int base = 0;
            if (myc) base = atomicAdd(cN, myc);          // one atomic per hitting thread
            unsigned mm = msk;
            while (mm) {
                int j = __builtin_ctz(mm); mm &= mm - 1;
                if (base < 1024) { cD[base] = d2a[j]; cI[base] = (unsigned short)(tid * 16 + j); }
                base++;
            }
            __syncthreads();   // B2
            int M = min(*cN, 1024);
            int n = min(M, K_);
            for (int i2 = tid; i2 < M; i2 += 256) {
                float di = cD[i2]; int ii = (int)cI[i2]; int r = 0;
                for (int j = 0; j < M; j++) {
                    float dj = cD[j];
                    r += (dj < di) || (dj == di && (int)cI[j] < ii);   // stable tie-break
                }
                if (r < K_) { nbrG[q * K_ + r] = (unsigned short)ii; sNbr[r] = (unsigned short)ii; }
            }
            if (tid == 0) { cnt[q] = n; atomicAdd(cntT, n); }
            __syncthreads();   // B3
            {   // gather x_j -> feat cols 0..63 (f16), zero rows >= n
                int row = tid >> 2, c4 = (tid & 3) * 16;
                half8 o0, o1;
                #pragma unroll
                for (int e = 0; e < 8; e++) { o0[e] = (_Float16)0.f; o1[e] = (_Float16)0.f; }
                if (row < n) {
                    const float4* xr = (const float4*)(x + ((size_t)b * N_ + sNbr[row]) * CIN + c4);
                    float4 v0 = xr[0], v1 = xr[1], v2 = xr[2], v3 = xr[3];
                    o0[0]=(_Float16)v0.x; o0[1]=(_Float16)v0.y; o0[2]=(_Float16)v0.z; o0[3]=(_Float16)v0.w;
                    o0[4]=(_Float16)v1.x; o0[5]=(_Float16)v1.y; o0[6]=(_Float16)v1.z; o0[7]=(_Float16)v1.w;
                    o1[0]=(_Float16)v2.x; o1[1]=(_Float16)v2.y; o1[2]=(_Float16)v2.z; o1[3]=(_Float16)v2.w;
                    o1[4]=(_Float16)v3.x; o1[5]=(_Float16)v3.y; o1[6]=(_Float16)v3.z; o1[7]=(_Float16)v3.w;
                }
                *(half8*)&sBuf[row * 104 + c4]     = o0;
                *(half8*)&sBuf[row * 104 + c4 + 8] = o1;
            }
            if (tid < 64) {   // cols 64..66 = pos_j - ctr, 67..95 = 0
                half8 z, o;
                #pragma unroll
                for (int e = 0; e < 8; e++) { z[e] = (_Float16)0.f; o[e] = (_Float16)0.f; }
                if (tid < n) {
                    int j = sNbr[tid];
                    const float* pj = pos + ((size_t)b * N_ + j) * 3;
                    o[0] = (_Float16)(pj[0] - cx); o[1] = (_Float16)(pj[1] - cy); o[2] = (_Float16)(pj[2] - cz);
                }
                *(half8*)&sBuf[tid * 104 + 64] = o;
                *(half8*)&sBuf[tid * 104 + 72] = z;
                *(half8*)&sBuf[tid * 104 + 80] = z;
                *(half8*)&sBuf[tid * 104 + 88] = z;
            }
            __syncthreads();   // B4
            floatx4 acc[4][2];
            #pragma unroll
            for (int rt = 0; rt < 4; rt++)
                #pragma unroll
                for (int nt = 0; nt < 2; nt++)
                    #pragma unroll
                    for (int r = 0; r < 4; r++) acc[rt][nt][r] = 0.f;
            #pragma unroll
            for (int ks = 0; ks < 3; ks++) {
                half8 av[4];
                #pragma unroll
                for (int rt = 0; rt < 4; rt++)
                    av[rt] = *(const half8*)&sBuf[(rt * 16 + lr) * 104 + ks * 32 + lq * 8];
                #pragma unroll
                for (int rt = 0; rt < 4; rt++)
                    #pragma unroll
                    for (int nt = 0; nt < 2; nt++)
                        acc[rt][nt] = __builtin_amdgcn_mfma_f32_16x16x32_f16(av[rt], w0f[ks][nt], acc[rt][nt], 0, 0, 0);
            }
            #pragma unroll
            for (int nt = 0; nt < 2; nt++) {
                int col = colbase + 16 * nt;
                float bias = sB0v[col];
                #pragma unroll
                for (int rt = 0; rt < 4; rt++) {
                    int r0 = rt * 16 + lq * 4;
                    #pragma unroll
                    for (int r = 0; r < 4; r++) {
                        float v = acc[rt][nt][r] + bias;
                        if (r0 + r < n) { runS1[nt] += v; runS2[nt] += v * v; }
                    }
                }
            }
        }
        #pragma unroll
        for (int nt = 0; nt < 2; nt++) {
            float s1 = runS1[nt], s2 = runS2[nt];
            s1 += __shfl_xor(s1, 16); s1 += __shfl_xor(s1, 32);
            s2 += __shfl_xor(s2, 16); s2 += __shfl_xor(s2, 32);
            if (lq == 0) {   // fixed-point (2^20) i64 atomics: deterministic
                int col = colbase + 16 * nt;
                atomicAdd(&statsOut[col],       (unsigned long long)(long long)llrintf(s1 * 1048576.f));
                atomicAdd(&statsOut[128 + col], (unsigned long long)(long long)llrintf(s2 * 1048576.f));
            }
        }
    }
}

// ---------------------------------------------------------------- BN params
__global__ void k_bnparam(const unsigned long long* __restrict__ stats, const int* __restrict__ cntT,
        const float* __restrict__ g, const float* __restrict__ be,
        float* __restrict__ scale, float* __restrict__ shift) {
    int t = threadIdx.x;
    double c = (double)(*cntT);
    double mean = (double)(long long)stats[t] * (1.0 / 1048576.0) / c;
    double ex2  = (double)(long long)stats[128 + t] * (1.0 / 1048576.0) / c;
    double var = ex2 - mean * mean;
    if (var < 0.0) var = 0.0;
    double sc = (double)g[t] / sqrt(var + 1e-5);
    scale[t] = (float)sc;
    shift[t] = (float)((double)be[t] - mean * sc);
}

// ---------------------------------------------------------------- fused MLP pass (r8 col-sliced, STAGE 1/2)
template<int STAGE>
__global__ __launch_bounds__(256, 2) void k_mlp(const float* __restrict__ x,
        const float* __restrict__ pos, const float* __restrict__ ctr,
        const unsigned short* __restrict__ nbr, const int* __restrict__ cnt,
        const _Float16* __restrict__ w0t, const _Float16* __restrict__ w1t,
        const _Float16* __restrict__ w2t,
        const float* __restrict__ b0, const float* __restrict__ b1,
        const float* __restrict__ b2,
        const float* __restrict__ sc0, const float* __restrict__ sh0,
        const float* __restrict__ sc1, const float* __restrict__ sh1,
        unsigned long long* __restrict__ statsOut, float* __restrict__ outF) {
    __shared__ __align__(16) _Float16 sBuf[64 * 136];   // feat(104) / h'(136)
    __shared__ unsigned short sNbr[64];
    __shared__ float sB0v[128];
    __shared__ float sB1v[128];
    __shared__ float sSc0[128];
    __shared__ float sSh0[128];
    __shared__ float sB2v[(STAGE >= 2) ? 128 : 4];
    __shared__ float sSc1[(STAGE >= 2) ? 128 : 4];
    __shared__ float sSh1[(STAGE >= 2) ? 128 : 4];

    int tid = threadIdx.x, wid = tid >> 6, lane = tid & 63;
    int lr = lane & 15, lq = lane >> 4;
    int colbase = 32 * wid + lr;

    half8 w0f[3][2];
    #pragma unroll
    for (int ks = 0; ks < 3; ks++)
        #pragma unroll
        for (int nt = 0; nt < 2; nt++)
            w0f[ks][nt] = *(const half8*)(w0t + (colbase + 16*nt) * 96 + ks * 32 + lq * 8);
    half8 w1f[4][2];
    #pragma unroll
    for (int ks = 0; ks < 4; ks++)
        #pragma unroll
        for (int nt = 0; nt < 2; nt++)
            w1f[ks][nt] = *(const half8*)(w1t + (colbase + 16*nt) * 128 + ks * 32 + lq * 8);
    half8 w2f[(STAGE >= 2) ? 4 : 1][2];
    if constexpr (STAGE >= 2)
        #pragma unroll
        for (int ks = 0; ks < 4; ks++)
            #pragma unroll
            for (int nt = 0; nt < 2; nt++)
                w2f[ks][nt] = *(const half8*)(w2t + (colbase + 16*nt) * 128 + ks * 32 + lq * 8);

    if (tid < 128) {
        sB0v[tid] = b0[tid];
        sB1v[tid] = b1[tid]; sSc0[tid] = sc0[tid]; sSh0[tid] = sh0[tid];
        if constexpr (STAGE >= 2) { sB2v[tid] = b2[tid]; sSc1[tid] = sc1[tid]; sSh1[tid] = sh1[tid]; }
    }
    float runS1[2] = {0.f, 0.f}, runS2[2] = {0.f, 0.f};

    for (int qq = 0; qq < 8; qq++) {
        int q = blockIdx.x * 8 + qq;
        int b = q >> 11;
        __syncthreads();                    // prior-iter sBuf readers done
        int n = cnt[q];
        if (tid < 64) sNbr[tid] = nbr[q * K_ + tid];
        __syncthreads();
        {   // gather x_j -> feat cols 0..63 (f16), zero rows >= n
            int row = tid >> 2, c4 = (tid & 3) * 16;
            half8 o0, o1;
            #pragma unroll
            for (int e = 0; e < 8; e++) { o0[e] = (_Float16)0.f; o1[e] = (_Float16)0.f; }
            if (row < n) {
                const float4* xr = (const float4*)(x + ((size_t)b * N_ + sNbr[row]) * CIN + c4);
                float4 v0 = xr[0], v1 = xr[1], v2 = xr[2], v3 = xr[3];
                o0[0]=(_Float16)v0.x; o0[1]=(_Float16)v0.y; o0[2]=(_Float16)v0.z; o0[3]=(_Float16)v0.w;
                o0[4]=(_Float16)v1.x; o0[5]=(_Float16)v1.y; o0[6]=(_Float16)v1.z; o0[7]=(_Float16)v1.w;
                o1[0]=(_Float16)v2.x; o1[1]=(_Float16)v2.y; o1[2]=(_Float16)v2.z; o1[3]=(_Float16)v2.w;
                o1[4]=(_Float16)v3.x; o1[5]=(_Float16)v3.y; o1[6]=(_Float16)v3.z; o1[7]=(_Float16)v3.w;
            }
            *(half8*)&sBuf[row * 104 + c4]     = o0;
            *(half8*)&sBuf[row * 104 + c4 + 8] = o1;
        }
        if (tid < 64) {
            half8 z, o;
            #pragma unroll
            for (int e = 0; e < 8; e++) { z[e] = (_Float16)0.f; o[e] = (_Float16)0.f; }
            if (tid < n) {
                int j = sNbr[tid];
                float cx = ctr[q*3], cy = ctr[q*3+1], cz = ctr[q*3+2];
                const float* pj = pos + ((size_t)b * N_ + j) * 3;
                o[0] = (_Float16)(pj[0] - cx); o[1] = (_Float16)(pj[1] - cy); o[2] = (_Float16)(pj[2] - cz);
            }
            *(half8*)&sBuf[tid * 104 + 64] = o;
            *(half8*)&sBuf[tid * 104 + 72] = z;
            *(half8*)&sBuf[tid * 104 + 80] = z;
            *(half8*)&sBuf[tid * 104 + 88] = z;
        }
        __syncthreads();

        // ---- GEMM0: K=96
        floatx4 acc[4][2];
        #pragma unroll
        for (int rt = 0; rt < 4; rt++)
            #pragma unroll
            for (int nt = 0; nt < 2; nt++)
                #pragma unroll
                for (int r = 0; r < 4; r++) acc[rt][nt][r] = 0.f;
        #pragma unroll
        for (int ks = 0; ks < 3; ks++) {
            half8 av[4];
            #pragma unroll
            for (int rt = 0; rt < 4; rt++)
                av[rt] = *(const half8*)&sBuf[(rt * 16 + lr) * 104 + ks * 32 + lq * 8];
            #pragma unroll
            for (int rt = 0; rt < 4; rt++)
                #pragma unroll
                for (int nt = 0; nt < 2; nt++)
                    acc[rt][nt] = __builtin_amdgcn_mfma_f32_16x16x32_f16(av[rt], w0f[ks][nt], acc[rt][nt], 0, 0, 0);
        }
        __syncthreads();

        // BN0 + ReLU -> f16 A-matrix for GEMM1
        #pragma unroll
        for (int nt = 0; nt < 2; nt++) {
            int col = colbase + 16 * nt;
            float bias = sB0v[col], s = sSc0[col], t2 = sSh0[col];
            #pragma unroll
            for (int rt = 0; rt < 4; rt++) {
                int r0 = rt * 16 + lq * 4;
                #pragma unroll
                for (int r = 0; r < 4; r++) {
                    float v = (acc[rt][nt][r] + bias) * s + t2;
                    sBuf[(r0 + r) * 136 + col] = (_Float16)fmaxf(v, 0.f);
                }
            }
        }
        __syncthreads();
        // ---- GEMM1: K=128
        #pragma unroll
        for (int rt = 0; rt < 4; rt++)
            #pragma unroll
            for (int nt = 0; nt < 2; nt++)
                #pragma unroll
                for (int r = 0; r < 4; r++) acc[rt][nt][r] = 0.f;
        #pragma unroll
        for (int ks = 0; ks < 4; ks++) {
            half8 av[4];
            #pragma unroll
            for (int rt = 0; rt < 4; rt++)
                av[rt] = *(const half8*)&sBuf[(rt * 16 + lr) * 136 + ks * 32 + lq * 8];
            #pragma unroll
            for (int rt = 0; rt < 4; rt++)
                #pragma unroll
                for (int nt = 0; nt < 2; nt++)
                    acc[rt][nt] = __builtin_amdgcn_mfma_f32_16x16x32_f16(av[rt], w1f[ks][nt], acc[rt][nt], 0, 0, 0);
        }

        if constexpr (STAGE == 1) {
            #pragma unroll
            for (int nt = 0; nt < 2; nt++) {
                int col = colbase + 16 * nt;
                float bias = sB1v[col];
                #pragma unroll
                for (int rt = 0; rt < 4; rt++) {
                    int r0 = rt * 16 + lq * 4;
                    #pragma unroll
                    for (int r = 0; r < 4; r++) {
                        float v = acc[rt][nt][r] + bias;
                        if (r0 + r < n) { runS1[nt] += v; runS2[nt] += v * v; }
                    }
                }
            }
        } else {
            __syncthreads();            // GEMM1 A-reads done before overwrite
            // BN1 + ReLU -> f16 A-matrix for GEMM2
            #pragma unroll
            for (int nt = 0; nt < 2; nt++) {
                int col = colbase + 16 * nt;
                float bias = sB1v[col], s = sSc1[col], t2 = sSh1[col];
                #pragma unroll
                for (int rt = 0; rt < 4; rt++) {
                    int r0 = rt * 16 + lq * 4;
                    #pragma unroll
                    for (int r = 0; r < 4; r++) {
                        float v = (acc[rt][nt][r] + bias) * s + t2;
                        sBuf[(r0 + r) * 136 + col] = (_Float16)fmaxf(v, 0.f);
                    }
                }
            }
            __syncthreads();
            // ---- GEMM2: K=128
            #pragma unroll
            for (int rt = 0; rt < 4; rt++)
                #pragma unroll
                for (int nt = 0; nt < 2; nt++)
                    #pragma unroll
                    for (int r = 0; r < 4; r++) acc[rt][nt][r] = 0.f;
            #pragma unroll
            for (int ks = 0; ks < 4; ks++) {
                half8 av[4];
                #pragma unroll
                for (int rt = 0; rt < 4; rt++)
                    av[rt] = *(const half8*)&sBuf[(rt * 16 + lr) * 136 + ks * 32 + lq * 8];
                #pragma unroll
                for (int rt = 0; rt < 4; rt++)
                    #pragma unroll
                    for (int nt = 0; nt < 2; nt++)
                        acc[rt][nt] = __builtin_amdgcn_mfma_f32_16x16x32_f16(av[rt], w2f[ks][nt], acc[rt][nt], 0, 0, 0);
            }
            // masked max over all rows (wave owns its cols) -> direct store
            #pragma unroll
            for (int nt = 0; nt < 2; nt++) {
                int col = colbase + 16 * nt;
                float bias = sB2v[col];
                float m = -__builtin_inff();
                #pragma unroll
                for (int rt = 0; rt < 4; rt++) {
                    int r0 = rt * 16 + lq * 4;
                    #pragma unroll
                    for (int r = 0; r < 4; r++)
                        if (r0 + r < n) m = fmaxf(m, acc[rt][nt][r] + bias);
                }
                m = fmaxf(m, __shfl_xor(m, 16));
                m = fmaxf(m, __shfl_xor(m, 32));
                if (lq == 0) outF[(size_t)q * 128 + col] = m;
            }
        }
    }
    if constexpr (STAGE == 1) {
        #pragma unroll
        for (int nt = 0; nt < 2; nt++) {
            float s1 = runS1[nt], s2 = runS2[nt];
            s1 += __shfl_xor(s1, 16); s1 += __shfl_xor(s1, 32);
            s2 += __shfl_xor(s2, 16); s2 += __shfl_xor(s2, 32);
            if (lq == 0) {
                int col = colbase + 16 * nt;
                atomicAdd(&statsOut[col],       (unsigned long long)(long long)llrintf(s1 * 1048576.f));
                atomicAdd(&statsOut[128 + col], (unsigned long long)(long long)llrintf(s2 * 1048576.f));
            }
        }
    }
}

// ---------------------------------------------------------------- launch
extern "C" void kernel_launch(void* const* d_in, const int* in_sizes, int n_in,
                              void* d_out, int out_size, void* d_ws, size_t ws_size,
                              hipStream_t stream) {
    const float* x   = (const float*)d_in[0];
    const float* pos = (const float*)d_in[1];
    const float* W0  = (const float*)d_in[3];
    const float* b0  = (const float*)d_in[4];
    const float* g0  = (const float*)d_in[5];
    const float* be0 = (const float*)d_in[6];
    const float* W1  = (const float*)d_in[7];
    const float* b1  = (const float*)d_in[8];
    const float* g1  = (const float*)d_in[9];
    const float* be1 = (const float*)d_in[10];
    const float* W2  = (const float*)d_in[11];
    const float* b2  = (const float*)d_in[12];

    char* ws = (char*)d_ws;
    unsigned long long* stats = (unsigned long long*)(ws + WS_STATS);
    int* cntT = (int*)(ws + WS_CNTT);
    _Float16* w0t = (_Float16*)(ws + WS_W0T);
    _Float16* w1t = (_Float16*)(ws + WS_W1T);
    _Float16* w2t = (_Float16*)(ws + WS_W2T);
    float* sc0 = (float*)(ws + WS_SC0);
    float* sh0 = (float*)(ws + WS_SH0);
    float* sc1 = (float*)(ws + WS_SC1);
    float* sh1 = (float*)(ws + WS_SH1);
    int* cnt = (int*)(ws + WS_CNT);
    unsigned short* nbr = (unsigned short*)(ws + WS_NBR);
    int* prog = (int*)(ws + WS_PROG);

    float* outF = (float*)d_out;                  // [16384,128]
    float* outCtr = (float*)d_out + 2097152;      // [16384,3]
    float* outBatch = (float*)d_out + 2146304;    // [16384]

    k_prep<<<176, 256, 0, stream>>>(W0, W1, W2, w0t, w1t, w2t, stats, cntT, prog);
    k_front<<<256, 256, 0, stream>>>(pos, x, w0t, b0, outCtr, outBatch, nbr, cnt, cntT,
            stats, prog);
    k_bnparam<<<1, 128, 0, stream>>>(stats, cntT, g0, be0, sc0, sh0);
    k_mlp<1><<<Q_/8, 256, 0, stream>>>(x, pos, outCtr, nbr, cnt, w0t, w1t, w2t,
            b0, b1, b2, sc0, sh0, sc1, sh1, stats + 256, outF);
    k_bnparam<<<1, 128, 0, stream>>>(stats + 256, cntT, g1, be1, sc1, sh1);
    k_mlp<2><<<Q_/8, 256, 0, stream>>>(x, pos, outCtr, nbr, cnt, w0t, w1t, w2t,
            b0, b1, b2, sc0, sh0, sc1, sh1, stats, outF);
}